// Round 3
// baseline (349.857 us; speedup 1.0000x reference)
//
#include <hip/hip_runtime.h>
#include <hip/hip_bf16.h>
#include <stdint.h>

typedef __bf16 bf16_t;
typedef __bf16 bf16x8 __attribute__((ext_vector_type(8)));
typedef float f32x4 __attribute__((ext_vector_type(4)));

#define NB      4
#define T_TXT   2048
#define T_IMG   8
#define N_LAT   64
#define DIM     2048
#define DIM_VIS 1024
#define HEADS   8
#define DHEAD   64
#define INNER   512

__device__ __forceinline__ void gld_lds16(const void* g, void* l) {
    __builtin_amdgcn_global_load_lds((const __attribute__((address_space(1))) void*)g,
                                     (__attribute__((address_space(3))) void*)l,
                                     16, 0, 0);
}

// ---------- transpose + fp32->bf16 convert: in fp32 (R x C) -> out bf16 (C x R)
__global__ __launch_bounds__(256) void transpose_cvt_k(const float* __restrict__ in,
                                                       bf16_t* __restrict__ out,
                                                       int R, int C) {
    __shared__ float tile[32][33];
    int c0 = blockIdx.x * 32, r0 = blockIdx.y * 32;
    int x = threadIdx.x, y = threadIdx.y;  // 32 x 8
#pragma unroll
    for (int d = 0; d < 4; d++)
        tile[y + d * 8][x] = in[(size_t)(r0 + y + d * 8) * C + c0 + x];
    __syncthreads();
#pragma unroll
    for (int d = 0; d < 4; d++)
        out[(size_t)(c0 + y + d * 8) * R + r0 + x] = (bf16_t)tile[x][y + d * 8];
}

// ---------- elementwise fp32 -> bf16 (n multiple of 2048) ---------------------
__global__ __launch_bounds__(256) void cvt_k(const float* __restrict__ in,
                                             bf16_t* __restrict__ out) {
    int idx = (blockIdx.x * 256 + threadIdx.x) * 8;
    f32x4 a = *(const f32x4*)(in + idx);
    f32x4 b = *(const f32x4*)(in + idx + 4);
    bf16x8 o;
#pragma unroll
    for (int i = 0; i < 4; i++) { o[i] = (bf16_t)a[i]; o[i + 4] = (bf16_t)b[i]; }
    *(bf16x8*)(out + idx) = o;
}

// ---------- LayerNorm: fp32 in, bf16 out; one block per row of 2048 -----------
__global__ __launch_bounds__(256) void ln_k(const float* __restrict__ x,
                                            const float* __restrict__ gamma,
                                            const float* __restrict__ beta,
                                            bf16_t* __restrict__ xn) {
    int row = blockIdx.x;
    int t = threadIdx.x;
    const float* xp = x + (size_t)row * DIM + t * 8;
    f32x4 v0 = *(const f32x4*)xp;
    f32x4 v1 = *(const f32x4*)(xp + 4);
    float f[8];
    float s = 0.f, ss = 0.f;
#pragma unroll
    for (int i = 0; i < 4; i++) { f[i] = v0[i]; f[i + 4] = v1[i]; }
#pragma unroll
    for (int i = 0; i < 8; i++) { s += f[i]; ss += f[i] * f[i]; }
#pragma unroll
    for (int off = 32; off > 0; off >>= 1) { s += __shfl_xor(s, off); ss += __shfl_xor(ss, off); }
    __shared__ float sbuf[4], sbuf2[4];
    int wid = t >> 6, lane = t & 63;
    if (lane == 0) { sbuf[wid] = s; sbuf2[wid] = ss; }
    __syncthreads();
    s  = sbuf[0] + sbuf[1] + sbuf[2] + sbuf[3];
    ss = sbuf2[0] + sbuf2[1] + sbuf2[2] + sbuf2[3];
    float mu  = s * (1.0f / DIM);
    float var = ss * (1.0f / DIM) - mu * mu;
    float rs  = rsqrtf(var + 1e-5f);
    f32x4 g0 = *(const f32x4*)(gamma + t * 8);
    f32x4 g1 = *(const f32x4*)(gamma + t * 8 + 4);
    f32x4 b0 = *(const f32x4*)(beta + t * 8);
    f32x4 b1 = *(const f32x4*)(beta + t * 8 + 4);
    bf16x8 o;
#pragma unroll
    for (int i = 0; i < 4; i++) {
        o[i]     = (bf16_t)((f[i]     - mu) * rs * g0[i] + b0[i]);
        o[i + 4] = (bf16_t)((f[i + 4] - mu) * rs * g1[i] + b1[i]);
    }
    *(bf16x8*)(xn + (size_t)row * DIM + t * 8) = o;
}

// ---------- GEMM: C[MxN] = A[MxK] * Bt[NxK]^T, bf16 in, fp32 accum, OT out ---
// 128x128 tile, BK=32, 4 waves in 2x2, each wave 4x4 of 16x16x32 MFMA tiles.
template <typename OT>
__global__ __launch_bounds__(256) void gemm_bt(const bf16_t* __restrict__ A,
                                               const bf16_t* __restrict__ Bt,
                                               OT* __restrict__ C,
                                               int M, int N, int K, float scale) {
    __shared__ __align__(16) bf16_t lA[128 * 32];
    __shared__ __align__(16) bf16_t lB[128 * 32];
    int tid = threadIdx.x;
    int w = tid >> 6, lane = tid & 63;
    int wm = w >> 1, wn = w & 1;
    int bm0 = blockIdx.y * 128, bn0 = blockIdx.x * 128;
    int q = lane >> 4, l16 = lane & 15;

    // staging: 16B chunk ids; chunk c covers row c>>2, col-chunk c&3 (8 bf16)
    int c0 = w * 64 + lane;
    int r0 = c0 >> 2, cc0 = c0 & 3;
    int c1 = 256 + c0;
    int r1 = c1 >> 2, cc1 = c1 & 3;
    const bf16_t* pA0 = A + (size_t)(bm0 + r0) * K + cc0 * 8;
    const bf16_t* pA1 = A + (size_t)(bm0 + r1) * K + cc1 * 8;
    const bf16_t* pB0 = Bt + (size_t)(bn0 + r0) * K + cc0 * 8;
    const bf16_t* pB1 = Bt + (size_t)(bn0 + r1) * K + cc1 * 8;
    bf16_t* lA0 = lA + w * 512;          // wave-uniform LDS bases (HW adds lane*16B)
    bf16_t* lA1 = lA + 2048 + w * 512;
    bf16_t* lB0 = lB + w * 512;
    bf16_t* lB1 = lB + 2048 + w * 512;

    f32x4 acc[4][4];
#pragma unroll
    for (int i = 0; i < 4; i++)
#pragma unroll
        for (int j = 0; j < 4; j++)
            acc[i][j] = (f32x4){0.f, 0.f, 0.f, 0.f};

    for (int k0 = 0; k0 < K; k0 += 32) {
        __syncthreads();              // prev iter's ds_reads done before overwrite
        gld_lds16(pA0 + k0, lA0);
        gld_lds16(pA1 + k0, lA1);
        gld_lds16(pB0 + k0, lB0);
        gld_lds16(pB1 + k0, lB1);
        __syncthreads();              // compiler drains vmcnt before barrier

        bf16x8 af[4], bfr[4];
#pragma unroll
        for (int mt = 0; mt < 4; mt++)
            af[mt] = *(const bf16x8*)(lA + (wm * 64 + mt * 16 + l16) * 32 + q * 8);
#pragma unroll
        for (int nt = 0; nt < 4; nt++)
            bfr[nt] = *(const bf16x8*)(lB + (wn * 64 + nt * 16 + l16) * 32 + q * 8);
#pragma unroll
        for (int mt = 0; mt < 4; mt++)
#pragma unroll
            for (int nt = 0; nt < 4; nt++)
                acc[mt][nt] = __builtin_amdgcn_mfma_f32_16x16x32_bf16(af[mt], bfr[nt], acc[mt][nt], 0, 0, 0);
    }

#pragma unroll
    for (int mt = 0; mt < 4; mt++)
#pragma unroll
        for (int nt = 0; nt < 4; nt++)
#pragma unroll
            for (int r = 0; r < 4; r++) {
                int row = bm0 + wm * 64 + mt * 16 + q * 4 + r;
                int col = bn0 + wn * 64 + nt * 16 + l16;
                C[(size_t)row * N + col] = (OT)(acc[mt][nt][r] * scale);
            }
}

// ---------- cumsum of media_locations -> text_time ----------------------------
// Storage mode auto-detected: uint8 / int32 / fp32(0.0,1.0). Detection reads
// only the first 8KB (in-bounds under every interpretation).
__global__ __launch_bounds__(256) void cumsum_k(const void* __restrict__ locs,
                                                int* __restrict__ text_time) {
    int b = blockIdx.x, t = threadIdx.x;
    const unsigned* up = (const unsigned*)locs;
    const int* ip = (const int*)locs;
    const unsigned char* bp = (const unsigned char*)locs;
    const float* fp = (const float*)locs;

    int other = 0, nf = 0;
#pragma unroll
    for (int i = 0; i < 8; i++) {
        unsigned wv = up[t * 8 + i];
        nf    += (wv == 0x3F800000u);
        other += (wv != 0u && wv != 1u && wv != 0x3F800000u);
    }
#pragma unroll
    for (int off = 32; off > 0; off >>= 1) { other += __shfl_xor(other, off); nf += __shfl_xor(nf, off); }
    __shared__ int so[4], sf[4];
    int wid = t >> 6, lane = t & 63;
    if (lane == 0) { so[wid] = other; sf[wid] = nf; }
    __syncthreads();
    other = so[0] + so[1] + so[2] + so[3];
    nf    = sf[0] + sf[1] + sf[2] + sf[3];
    int mode = (other > 0) ? 0 : ((nf > 0) ? 2 : 1);   // 0=u8, 1=i32, 2=f32

    int v[8];
    int s = 0;
#pragma unroll
    for (int i = 0; i < 8; i++) {
        int idx = b * T_TXT + t * 8 + i;
        int xv;
        if (mode == 1)      xv = ip[idx];
        else if (mode == 0) xv = (int)bp[idx];
        else                xv = (fp[idx] != 0.f) ? 1 : 0;
        v[i] = xv;
        s += xv;
    }
    __shared__ int sc[256];
    sc[t] = s;
    __syncthreads();
    for (int off = 1; off < 256; off <<= 1) {
        int add = (t >= off) ? sc[t - off] : 0;
        __syncthreads();
        sc[t] += add;
        __syncthreads();
    }
    int run = sc[t] - s;   // exclusive prefix of this thread's chunk
#pragma unroll
    for (int i = 0; i < 8; i++) {
        run += v[i];
        text_time[b * T_TXT + t * 8 + i] = run;
    }
}

// ---------- attention: one wave per (head, query) -----------------------------
// q: [8192 x 512] bf16 (already *0.125); kv: [2048 x 1024] bf16 (k 0..511, v 512..1023)
// attn_out may ALIAS q: each wave reads only its own 64-elem q block (fully
// consumed before the final write to the same 64-elem out block).
__global__ __launch_bounds__(256) void attn_k(const bf16_t* __restrict__ q,
                                              const bf16_t* __restrict__ kv,
                                              const int* __restrict__ text_time,
                                              bf16_t* __restrict__ attn_out) {
    int lane = threadIdx.x & 63, wid = threadIdx.x >> 6;
    int gid = blockIdx.x * 4 + wid;          // 0..65535
    int h = gid >> 13;                       // 0..7
    int row = gid & 8191;                    // b*2048 + i
    int b = row >> 11;
    int t = text_time[row];
    bf16_t* outp = attn_out + (size_t)row * INNER + h * DHEAD;
    if (t == 0) { outp[lane] = (bf16_t)0.f; return; }

    const bf16_t* qb = q + (size_t)row * INNER + h * DHEAD;
    size_t krow0 = (size_t)(b * (T_IMG * N_LAT) + (t - 1) * N_LAT);
    const bf16_t* kp = kv + (krow0 + lane) * (2 * INNER) + h * DHEAD;  // lane = key jj

    float s = 0.f;
#pragma unroll
    for (int c = 0; c < 8; c++) {
        bf16x8 q8 = *(const bf16x8*)(qb + c * 8);   // broadcast across lanes
        bf16x8 k8 = *(const bf16x8*)(kp + c * 8);
#pragma unroll
        for (int u = 0; u < 8; u++) s += (float)q8[u] * (float)k8[u];
    }
    float m = s;
#pragma unroll
    for (int off = 32; off > 0; off >>= 1) m = fmaxf(m, __shfl_xor(m, off));
    float p = __expf(s - m);
    float l = p;
#pragma unroll
    for (int off = 32; off > 0; off >>= 1) l += __shfl_xor(l, off);
    p /= l;

    // PV: lane = output dim d; iterate keys, broadcast p via shfl, coalesced v rows
    const bf16_t* vbase = kv + krow0 * (2 * INNER) + INNER + h * DHEAD + lane;
    float acc = 0.f;
#pragma unroll
    for (int jj = 0; jj < 64; jj++) {
        float pj = __shfl(p, jj);
        acc += pj * (float)vbase[(size_t)jj * (2 * INNER)];
    }
    outp[lane] = (bf16_t)acc;
}

// ---------- launch ------------------------------------------------------------
extern "C" void kernel_launch(void* const* d_in, const int* in_sizes, int n_in,
                              void* d_out, int out_size, void* d_ws, size_t ws_size,
                              hipStream_t stream) {
    const float* x     = (const float*)d_in[0];
    const float* media = (const float*)d_in[1];
    const void*  locs  = d_in[2];
    const float* gamma = (const float*)d_in[3];
    const float* beta  = (const float*)d_in[4];
    const float* Wq    = (const float*)d_in[5];
    const float* Wkv   = (const float*)d_in[6];
    const float* Wout  = (const float*)d_in[7];
    float* out = (float*)d_out;

    // xn (bf16, 32MB) lives in d_out (fp32, 64MB): dead before final GEMM writes.
    bf16_t* xn = (bf16_t*)d_out;

    char* p = (char*)d_ws;
    bf16_t* qbuf   = (bf16_t*)p; p += (size_t)8192 * 512 * 2;    // 8 MB (reused as aout)
    bf16_t* kvbuf  = (bf16_t*)p; p += (size_t)2048 * 1024 * 2;   // 4 MB
    bf16_t* mediab = (bf16_t*)p; p += (size_t)2048 * 1024 * 2;   // 4 MB
    bf16_t* WqT    = (bf16_t*)p; p += (size_t)512 * 2048 * 2;    // 2 MB
    bf16_t* WkvT   = (bf16_t*)p; p += (size_t)1024 * 1024 * 2;   // 2 MB
    bf16_t* WoutT  = (bf16_t*)p; p += (size_t)2048 * 512 * 2;    // 2 MB
    int*    ttime  = (int*)p;    p += (size_t)8192 * 4;
    bf16_t* aout   = qbuf;   // safe alias (see attn_k)

    transpose_cvt_k<<<dim3(512 / 32, 2048 / 32), dim3(32, 8), 0, stream>>>(Wq, WqT, 2048, 512);
    transpose_cvt_k<<<dim3(1024 / 32, 1024 / 32), dim3(32, 8), 0, stream>>>(Wkv, WkvT, 1024, 1024);
    transpose_cvt_k<<<dim3(2048 / 32, 512 / 32), dim3(32, 8), 0, stream>>>(Wout, WoutT, 512, 2048);
    cvt_k<<<(2048 * 1024) / (256 * 8), 256, 0, stream>>>(media, mediab);

    ln_k<<<8192, 256, 0, stream>>>(x, gamma, beta, xn);

    // q = xn @ Wq * 0.125   (8192x2048 @ 2048x512)
    gemm_bt<bf16_t><<<dim3(512 / 128, 8192 / 128), 256, 0, stream>>>(xn, WqT, qbuf, 8192, 512, 2048, 0.125f);
    // kv = media @ Wkv      (2048x1024 @ 1024x1024)
    gemm_bt<bf16_t><<<dim3(1024 / 128, 2048 / 128), 256, 0, stream>>>(mediab, WkvT, kvbuf, 2048, 1024, 1024, 1.0f);

    cumsum_k<<<NB, 256, 0, stream>>>(locs, ttime);

    attn_k<<<16384, 256, 0, stream>>>(qbuf, kvbuf, ttime, aout);

    // out = aout @ Wout     (8192x512 @ 512x2048), fp32 store to d_out
    gemm_bt<float><<<dim3(2048 / 128, 8192 / 128), 256, 0, stream>>>(aout, WoutT, out, 8192, 2048, 512, 1.0f);
}

// Round 4
// 322.572 us; speedup vs baseline: 1.0846x; 1.0846x over previous
//
#include <hip/hip_runtime.h>
#include <hip/hip_bf16.h>
#include <stdint.h>

typedef __bf16 bf16_t;
typedef __bf16 bf16x8 __attribute__((ext_vector_type(8)));
typedef float f32x4 __attribute__((ext_vector_type(4)));

#define NB      4
#define T_TXT   2048
#define T_IMG   8
#define N_LAT   64
#define DIM     2048
#define DIM_VIS 1024
#define HEADS   8
#define DHEAD   64
#define INNER   512

__device__ __forceinline__ void gld_lds16(const void* g, void* l) {
    __builtin_amdgcn_global_load_lds((const __attribute__((address_space(1))) void*)g,
                                     (__attribute__((address_space(3))) void*)l,
                                     16, 0, 0);
}

// ---------- transpose + fp32->bf16 convert: in fp32 (R x C) -> out bf16 (C x R)
__global__ __launch_bounds__(256) void transpose_cvt_k(const float* __restrict__ in,
                                                       bf16_t* __restrict__ out,
                                                       int R, int C) {
    __shared__ float tile[32][33];
    int c0 = blockIdx.x * 32, r0 = blockIdx.y * 32;
    int x = threadIdx.x, y = threadIdx.y;  // 32 x 8
#pragma unroll
    for (int d = 0; d < 4; d++)
        tile[y + d * 8][x] = in[(size_t)(r0 + y + d * 8) * C + c0 + x];
    __syncthreads();
#pragma unroll
    for (int d = 0; d < 4; d++)
        out[(size_t)(c0 + y + d * 8) * R + r0 + x] = (bf16_t)tile[x][y + d * 8];
}

// ---------- elementwise fp32 -> bf16 ------------------------------------------
__global__ __launch_bounds__(256) void cvt_k(const float* __restrict__ in,
                                             bf16_t* __restrict__ out) {
    int idx = (blockIdx.x * 256 + threadIdx.x) * 8;
    f32x4 a = *(const f32x4*)(in + idx);
    f32x4 b = *(const f32x4*)(in + idx + 4);
    bf16x8 o;
#pragma unroll
    for (int i = 0; i < 4; i++) { o[i] = (bf16_t)a[i]; o[i + 4] = (bf16_t)b[i]; }
    *(bf16x8*)(out + idx) = o;
}

// ---------- LayerNorm: fp32 in, bf16 out; one block per row of 2048 -----------
__global__ __launch_bounds__(256) void ln_k(const float* __restrict__ x,
                                            const float* __restrict__ gamma,
                                            const float* __restrict__ beta,
                                            bf16_t* __restrict__ xn) {
    int row = blockIdx.x;
    int t = threadIdx.x;
    const float* xp = x + (size_t)row * DIM + t * 8;
    f32x4 v0 = *(const f32x4*)xp;
    f32x4 v1 = *(const f32x4*)(xp + 4);
    float f[8];
    float s = 0.f, ss = 0.f;
#pragma unroll
    for (int i = 0; i < 4; i++) { f[i] = v0[i]; f[i + 4] = v1[i]; }
#pragma unroll
    for (int i = 0; i < 8; i++) { s += f[i]; ss += f[i] * f[i]; }
#pragma unroll
    for (int off = 32; off > 0; off >>= 1) { s += __shfl_xor(s, off); ss += __shfl_xor(ss, off); }
    __shared__ float sbuf[4], sbuf2[4];
    int wid = t >> 6, lane = t & 63;
    if (lane == 0) { sbuf[wid] = s; sbuf2[wid] = ss; }
    __syncthreads();
    s  = sbuf[0] + sbuf[1] + sbuf[2] + sbuf[3];
    ss = sbuf2[0] + sbuf2[1] + sbuf2[2] + sbuf2[3];
    float mu  = s * (1.0f / DIM);
    float var = ss * (1.0f / DIM) - mu * mu;
    float rs  = rsqrtf(var + 1e-5f);
    f32x4 g0 = *(const f32x4*)(gamma + t * 8);
    f32x4 g1 = *(const f32x4*)(gamma + t * 8 + 4);
    f32x4 b0 = *(const f32x4*)(beta + t * 8);
    f32x4 b1 = *(const f32x4*)(beta + t * 8 + 4);
    bf16x8 o;
#pragma unroll
    for (int i = 0; i < 4; i++) {
        o[i]     = (bf16_t)((f[i]     - mu) * rs * g0[i] + b0[i]);
        o[i + 4] = (bf16_t)((f[i + 4] - mu) * rs * g1[i] + b1[i]);
    }
    *(bf16x8*)(xn + (size_t)row * DIM + t * 8) = o;
}

// ---------- GEMM: C[MxN] = A[MxK] * Bt[NxK]^T, bf16 in, fp32 accum, OT out ---
template <typename OT>
__global__ __launch_bounds__(256) void gemm_bt(const bf16_t* __restrict__ A,
                                               const bf16_t* __restrict__ Bt,
                                               OT* __restrict__ C,
                                               int M, int N, int K, float scale) {
    __shared__ __align__(16) bf16_t lA[128 * 32];
    __shared__ __align__(16) bf16_t lB[128 * 32];
    int tid = threadIdx.x;
    int w = tid >> 6, lane = tid & 63;
    int wm = w >> 1, wn = w & 1;
    int bm0 = blockIdx.y * 128, bn0 = blockIdx.x * 128;
    int q = lane >> 4, l16 = lane & 15;

    int c0 = w * 64 + lane;
    int r0 = c0 >> 2, cc0 = c0 & 3;
    int c1 = 256 + c0;
    int r1 = c1 >> 2, cc1 = c1 & 3;
    const bf16_t* pA0 = A + (size_t)(bm0 + r0) * K + cc0 * 8;
    const bf16_t* pA1 = A + (size_t)(bm0 + r1) * K + cc1 * 8;
    const bf16_t* pB0 = Bt + (size_t)(bn0 + r0) * K + cc0 * 8;
    const bf16_t* pB1 = Bt + (size_t)(bn0 + r1) * K + cc1 * 8;
    bf16_t* lA0 = lA + w * 512;
    bf16_t* lA1 = lA + 2048 + w * 512;
    bf16_t* lB0 = lB + w * 512;
    bf16_t* lB1 = lB + 2048 + w * 512;

    f32x4 acc[4][4];
#pragma unroll
    for (int i = 0; i < 4; i++)
#pragma unroll
        for (int j = 0; j < 4; j++)
            acc[i][j] = (f32x4){0.f, 0.f, 0.f, 0.f};

    for (int k0 = 0; k0 < K; k0 += 32) {
        __syncthreads();
        gld_lds16(pA0 + k0, lA0);
        gld_lds16(pA1 + k0, lA1);
        gld_lds16(pB0 + k0, lB0);
        gld_lds16(pB1 + k0, lB1);
        __syncthreads();

        bf16x8 af[4], bfr[4];
#pragma unroll
        for (int mt = 0; mt < 4; mt++)
            af[mt] = *(const bf16x8*)(lA + (wm * 64 + mt * 16 + l16) * 32 + q * 8);
#pragma unroll
        for (int nt = 0; nt < 4; nt++)
            bfr[nt] = *(const bf16x8*)(lB + (wn * 64 + nt * 16 + l16) * 32 + q * 8);
#pragma unroll
        for (int mt = 0; mt < 4; mt++)
#pragma unroll
            for (int nt = 0; nt < 4; nt++)
                acc[mt][nt] = __builtin_amdgcn_mfma_f32_16x16x32_bf16(af[mt], bfr[nt], acc[mt][nt], 0, 0, 0);
    }

#pragma unroll
    for (int mt = 0; mt < 4; mt++)
#pragma unroll
        for (int nt = 0; nt < 4; nt++)
#pragma unroll
            for (int r = 0; r < 4; r++) {
                int row = bm0 + wm * 64 + mt * 16 + q * 4 + r;
                int col = bn0 + wn * 64 + nt * 16 + l16;
                C[(size_t)row * N + col] = (OT)(acc[mt][nt][r] * scale);
            }
}

// ---------- cumsum + bucket build ---------------------------------------------
// text_time cumsum per batch row; scatter query indices into per-(b,t) buckets.
// Storage mode auto-detected: uint8 / int32 / fp32 (reads first 8KB only).
__global__ __launch_bounds__(256) void cumsum_bucket_k(const void* __restrict__ locs,
                                                       int* __restrict__ bcount,
                                                       int* __restrict__ bidx) {
    int b = blockIdx.x, t = threadIdx.x;
    const unsigned* up = (const unsigned*)locs;
    const int* ip = (const int*)locs;
    const unsigned char* bp = (const unsigned char*)locs;
    const float* fp = (const float*)locs;

    if (t < T_IMG) bcount[b * T_IMG + t] = 0;

    int other = 0, nf = 0;
#pragma unroll
    for (int i = 0; i < 8; i++) {
        unsigned wv = up[t * 8 + i];
        nf    += (wv == 0x3F800000u);
        other += (wv != 0u && wv != 1u && wv != 0x3F800000u);
    }
#pragma unroll
    for (int off = 32; off > 0; off >>= 1) { other += __shfl_xor(other, off); nf += __shfl_xor(nf, off); }
    __shared__ int so[4], sf[4];
    int wid = t >> 6, lane = t & 63;
    if (lane == 0) { so[wid] = other; sf[wid] = nf; }
    __syncthreads();
    other = so[0] + so[1] + so[2] + so[3];
    nf    = sf[0] + sf[1] + sf[2] + sf[3];
    int mode = (other > 0) ? 0 : ((nf > 0) ? 2 : 1);   // 0=u8, 1=i32, 2=f32

    int v[8];
    int s = 0;
#pragma unroll
    for (int i = 0; i < 8; i++) {
        int idx = b * T_TXT + t * 8 + i;
        int xv;
        if (mode == 1)      xv = ip[idx];
        else if (mode == 0) xv = (int)bp[idx];
        else                xv = (fp[idx] != 0.f) ? 1 : 0;
        v[i] = xv;
        s += xv;
    }
    __shared__ int sc[256];
    sc[t] = s;
    __syncthreads();
    for (int off = 1; off < 256; off <<= 1) {
        int add = (t >= off) ? sc[t - off] : 0;
        __syncthreads();
        sc[t] += add;
        __syncthreads();
    }
    int run = sc[t] - s;
#pragma unroll
    for (int i = 0; i < 8; i++) {
        run += v[i];
        if (run > 0) {
            int bk = b * T_IMG + run - 1;
            int pos = atomicAdd(&bcount[bk], 1);
            bidx[bk * T_TXT + pos] = b * T_TXT + t * 8 + i;
        }
    }
}

// ---------- MFMA bucketed attention -------------------------------------------
// Block = (bucket = b*8 + timg, head). Stages K_h [64x64] row-major and
// V_h transposed [d][key] into LDS; each wave handles 16-query chunks:
// QK^T (8 MFMA) -> quad-shuffle softmax -> P via wave-private LDS (C->A layout)
// -> PV (8 MFMA) -> scatter store. q is pre-scaled by 0.125.
__global__ __launch_bounds__(256) void attn_mfma_k(const bf16_t* __restrict__ q,
                                                   const bf16_t* __restrict__ kv,
                                                   const int* __restrict__ bcount,
                                                   const int* __restrict__ bidx,
                                                   bf16_t* __restrict__ aout) {
    __shared__ __align__(16) bf16_t lK[64 * 64];
    __shared__ __align__(16) bf16_t lVt[64 * 64];
    __shared__ __align__(16) bf16_t lP[4][16 * 64];

    int bucket = blockIdx.x >> 3;
    int h = blockIdx.x & 7;
    int n_q = bcount[bucket];
    if (n_q <= 0) return;
    int b = bucket >> 3;
    int timg = bucket & 7;
    size_t krow0 = (size_t)(b * (T_IMG * N_LAT) + timg * N_LAT);

    int tid = threadIdx.x;
    int wid = tid >> 6, lane = tid & 63;
    int quad = lane >> 4, l16 = lane & 15;

    // K_h staging: wave wid -> rows 16*wid .. 16*wid+15 (2x gld_lds16)
    {
        const bf16_t* s0 = kv + (krow0 + 16 * wid + (lane >> 3)) * (2 * INNER) + h * DHEAD + (lane & 7) * 8;
        const bf16_t* s1 = kv + (krow0 + 16 * wid + 8 + (lane >> 3)) * (2 * INNER) + h * DHEAD + (lane & 7) * 8;
        gld_lds16(s0, lK + wid * 1024);
        gld_lds16(s1, lK + wid * 1024 + 512);
    }
    // V_h^T staging: thread: key=tid&63, d-block=tid>>6 (16 d's)
    {
        int key = tid & 63, dblk = tid >> 6;
        const bf16_t* vsrc = kv + (krow0 + key) * (2 * INNER) + INNER + h * DHEAD + dblk * 16;
        bf16x8 v0 = *(const bf16x8*)vsrc;
        bf16x8 v1 = *(const bf16x8*)(vsrc + 8);
#pragma unroll
        for (int u = 0; u < 8; u++) {
            lVt[(dblk * 16 + u) * 64 + key]     = v0[u];
            lVt[(dblk * 16 + 8 + u) * 64 + key] = v1[u];
        }
    }
    __syncthreads();

    const int* bl = bidx + (size_t)bucket * T_TXT;
    for (int c0 = wid * 16; c0 < n_q; c0 += 64) {
        int qi = bl[c0 + ((c0 + l16 < n_q) ? l16 : 0)];

        // QK^T: S[16q x 64key] over K=64 (2 k-steps)
        const bf16_t* qrow = q + (size_t)qi * INNER + h * DHEAD + quad * 8;
        bf16x8 qf0 = *(const bf16x8*)qrow;
        bf16x8 qf1 = *(const bf16x8*)(qrow + 32);
        f32x4 s[4];
#pragma unroll
        for (int nt = 0; nt < 4; nt++) s[nt] = (f32x4){0.f, 0.f, 0.f, 0.f};
#pragma unroll
        for (int nt = 0; nt < 4; nt++) {
            bf16x8 kf0 = *(const bf16x8*)(lK + (l16 + 16 * nt) * 64 + quad * 8);
            bf16x8 kf1 = *(const bf16x8*)(lK + (l16 + 16 * nt) * 64 + 32 + quad * 8);
            s[nt] = __builtin_amdgcn_mfma_f32_16x16x32_bf16(qf0, kf0, s[nt], 0, 0, 0);
            s[nt] = __builtin_amdgcn_mfma_f32_16x16x32_bf16(qf1, kf1, s[nt], 0, 0, 0);
        }

        // row softmax (row = quad*4+r lives across the 16 l16 lanes of the quad)
        float mr[4];
#pragma unroll
        for (int r = 0; r < 4; r++) {
            float m = fmaxf(fmaxf(s[0][r], s[1][r]), fmaxf(s[2][r], s[3][r]));
#pragma unroll
            for (int off = 8; off >= 1; off >>= 1) m = fmaxf(m, __shfl_xor(m, off));
            mr[r] = m;
        }
        float p[4][4];
#pragma unroll
        for (int nt = 0; nt < 4; nt++)
#pragma unroll
            for (int r = 0; r < 4; r++)
                p[nt][r] = __expf(s[nt][r] - mr[r]);
#pragma unroll
        for (int r = 0; r < 4; r++) {
            float tsum = p[0][r] + p[1][r] + p[2][r] + p[3][r];
#pragma unroll
            for (int off = 8; off >= 1; off >>= 1) tsum += __shfl_xor(tsum, off);
            float inv = 1.0f / tsum;
            p[0][r] *= inv; p[1][r] *= inv; p[2][r] *= inv; p[3][r] *= inv;
        }

        // C-layout -> A-layout via wave-private LDS tile
        bf16_t* pt = lP[wid];
#pragma unroll
        for (int nt = 0; nt < 4; nt++)
#pragma unroll
            for (int r = 0; r < 4; r++)
                pt[(quad * 4 + r) * 64 + 16 * nt + l16] = (bf16_t)p[nt][r];
        asm volatile("s_waitcnt lgkmcnt(0)" ::: "memory");

        // PV: O[16q x 64d] over K=64 keys (2 k-steps)
        bf16x8 pf0 = *(const bf16x8*)(pt + l16 * 64 + quad * 8);
        bf16x8 pf1 = *(const bf16x8*)(pt + l16 * 64 + 32 + quad * 8);
        f32x4 o[4];
#pragma unroll
        for (int ntd = 0; ntd < 4; ntd++) o[ntd] = (f32x4){0.f, 0.f, 0.f, 0.f};
#pragma unroll
        for (int ntd = 0; ntd < 4; ntd++) {
            bf16x8 vf0 = *(const bf16x8*)(lVt + (l16 + 16 * ntd) * 64 + quad * 8);
            bf16x8 vf1 = *(const bf16x8*)(lVt + (l16 + 16 * ntd) * 64 + 32 + quad * 8);
            o[ntd] = __builtin_amdgcn_mfma_f32_16x16x32_bf16(pf0, vf0, o[ntd], 0, 0, 0);
            o[ntd] = __builtin_amdgcn_mfma_f32_16x16x32_bf16(pf1, vf1, o[ntd], 0, 0, 0);
        }

        // store: row = quad*4+r (query), col = l16 + 16*ntd (head dim)
#pragma unroll
        for (int r = 0; r < 4; r++) {
            int row = quad * 4 + r;
            int qo = __shfl(qi, row);
            if (c0 + row < n_q) {
                bf16_t* op = aout + (size_t)qo * INNER + h * DHEAD + l16;
#pragma unroll
                for (int ntd = 0; ntd < 4; ntd++)
                    op[16 * ntd] = (bf16_t)o[ntd][r];
            }
        }
    }
}

// ---------- launch ------------------------------------------------------------
extern "C" void kernel_launch(void* const* d_in, const int* in_sizes, int n_in,
                              void* d_out, int out_size, void* d_ws, size_t ws_size,
                              hipStream_t stream) {
    const float* x     = (const float*)d_in[0];
    const float* media = (const float*)d_in[1];
    const void*  locs  = d_in[2];
    const float* gamma = (const float*)d_in[3];
    const float* beta  = (const float*)d_in[4];
    const float* Wq    = (const float*)d_in[5];
    const float* Wkv   = (const float*)d_in[6];
    const float* Wout  = (const float*)d_in[7];
    float* out = (float*)d_out;

    // xn (bf16, 32MB) lives in d_out (fp32, 64MB): dead before final GEMM writes.
    bf16_t* xn = (bf16_t*)d_out;

    char* p = (char*)d_ws;
    bf16_t* qbuf   = (bf16_t*)p; p += (size_t)8192 * 512 * 2;    // 8 MB
    bf16_t* aout   = (bf16_t*)p; p += (size_t)8192 * 512 * 2;    // 8 MB
    bf16_t* kvbuf  = (bf16_t*)p; p += (size_t)2048 * 1024 * 2;   // 4 MB
    bf16_t* mediab = (bf16_t*)p; p += (size_t)2048 * 1024 * 2;   // 4 MB
    bf16_t* WqT    = (bf16_t*)p; p += (size_t)512 * 2048 * 2;    // 2 MB
    bf16_t* WkvT   = (bf16_t*)p; p += (size_t)1024 * 1024 * 2;   // 2 MB
    bf16_t* WoutT  = (bf16_t*)p; p += (size_t)2048 * 512 * 2;    // 2 MB
    int*    bcount = (int*)p;    p += 32 * sizeof(int);
    int*    bidx   = (int*)p;    p += (size_t)32 * T_TXT * sizeof(int);  // 256 KB

    transpose_cvt_k<<<dim3(512 / 32, 2048 / 32), dim3(32, 8), 0, stream>>>(Wq, WqT, 2048, 512);
    transpose_cvt_k<<<dim3(1024 / 32, 1024 / 32), dim3(32, 8), 0, stream>>>(Wkv, WkvT, 1024, 1024);
    transpose_cvt_k<<<dim3(2048 / 32, 512 / 32), dim3(32, 8), 0, stream>>>(Wout, WoutT, 512, 2048);
    cvt_k<<<(2048 * 1024) / (256 * 8), 256, 0, stream>>>(media, mediab);

    ln_k<<<8192, 256, 0, stream>>>(x, gamma, beta, xn);

    // q = xn @ Wq * 0.125   (8192x2048 @ 2048x512)
    gemm_bt<bf16_t><<<dim3(512 / 128, 8192 / 128), 256, 0, stream>>>(xn, WqT, qbuf, 8192, 512, 2048, 0.125f);
    // kv = media @ Wkv      (2048x1024 @ 1024x1024)
    gemm_bt<bf16_t><<<dim3(1024 / 128, 2048 / 128), 256, 0, stream>>>(mediab, WkvT, kvbuf, 2048, 1024, 1024, 1.0f);

    cumsum_bucket_k<<<NB, 256, 0, stream>>>(locs, bcount, bidx);

    // t==0 rows must be zero; memset whole aout, attn overwrites bucketed rows.
    hipMemsetAsync(aout, 0, (size_t)8192 * 512 * 2, stream);

    attn_mfma_k<<<32 * HEADS, 256, 0, stream>>>(qbuf, kvbuf, bcount, bidx, aout);

    // out = aout @ Wout     (8192x512 @ 512x2048), fp32 store to d_out
    gemm_bt<float><<<dim3(2048 / 128, 8192 / 128), 256, 0, stream>>>(aout, WoutT, out, 8192, 2048, 512, 1.0f);
}

// Round 5
// 314.136 us; speedup vs baseline: 1.1137x; 1.0269x over previous
//
#include <hip/hip_runtime.h>
#include <hip/hip_bf16.h>
#include <stdint.h>

typedef __bf16 bf16_t;
typedef __bf16 bf16x8 __attribute__((ext_vector_type(8)));
typedef float f32x4 __attribute__((ext_vector_type(4)));

#define NB      4
#define T_TXT   2048
#define T_IMG   8
#define N_LAT   64
#define DIM     2048
#define DIM_VIS 1024
#define HEADS   8
#define DHEAD   64
#define INNER   512

__device__ __forceinline__ void gld_lds16(const void* g, void* l) {
    __builtin_amdgcn_global_load_lds((const __attribute__((address_space(1))) void*)g,
                                     (__attribute__((address_space(3))) void*)l,
                                     16, 0, 0);
}

// ---------- transpose + fp32->bf16 convert: in fp32 (R x C) -> out bf16 (C x R)
__global__ __launch_bounds__(256) void transpose_cvt_k(const float* __restrict__ in,
                                                       bf16_t* __restrict__ out,
                                                       int R, int C) {
    __shared__ float tile[32][33];
    int c0 = blockIdx.x * 32, r0 = blockIdx.y * 32;
    int x = threadIdx.x, y = threadIdx.y;  // 32 x 8
#pragma unroll
    for (int d = 0; d < 4; d++)
        tile[y + d * 8][x] = in[(size_t)(r0 + y + d * 8) * C + c0 + x];
    __syncthreads();
#pragma unroll
    for (int d = 0; d < 4; d++)
        out[(size_t)(c0 + y + d * 8) * R + r0 + x] = (bf16_t)tile[x][y + d * 8];
}

// ---------- elementwise fp32 -> bf16 ------------------------------------------
__global__ __launch_bounds__(256) void cvt_k(const float* __restrict__ in,
                                             bf16_t* __restrict__ out) {
    int idx = (blockIdx.x * 256 + threadIdx.x) * 8;
    f32x4 a = *(const f32x4*)(in + idx);
    f32x4 b = *(const f32x4*)(in + idx + 4);
    bf16x8 o;
#pragma unroll
    for (int i = 0; i < 4; i++) { o[i] = (bf16_t)a[i]; o[i + 4] = (bf16_t)b[i]; }
    *(bf16x8*)(out + idx) = o;
}

// ---------- LayerNorm: fp32 in, bf16 out; one block per row of 2048 -----------
__global__ __launch_bounds__(256) void ln_k(const float* __restrict__ x,
                                            const float* __restrict__ gamma,
                                            const float* __restrict__ beta,
                                            bf16_t* __restrict__ xn) {
    int row = blockIdx.x;
    int t = threadIdx.x;
    const float* xp = x + (size_t)row * DIM + t * 8;
    f32x4 v0 = *(const f32x4*)xp;
    f32x4 v1 = *(const f32x4*)(xp + 4);
    float f[8];
    float s = 0.f, ss = 0.f;
#pragma unroll
    for (int i = 0; i < 4; i++) { f[i] = v0[i]; f[i + 4] = v1[i]; }
#pragma unroll
    for (int i = 0; i < 8; i++) { s += f[i]; ss += f[i] * f[i]; }
#pragma unroll
    for (int off = 32; off > 0; off >>= 1) { s += __shfl_xor(s, off); ss += __shfl_xor(ss, off); }
    __shared__ float sbuf[4], sbuf2[4];
    int wid = t >> 6, lane = t & 63;
    if (lane == 0) { sbuf[wid] = s; sbuf2[wid] = ss; }
    __syncthreads();
    s  = sbuf[0] + sbuf[1] + sbuf[2] + sbuf[3];
    ss = sbuf2[0] + sbuf2[1] + sbuf2[2] + sbuf2[3];
    float mu  = s * (1.0f / DIM);
    float var = ss * (1.0f / DIM) - mu * mu;
    float rs  = rsqrtf(var + 1e-5f);
    f32x4 g0 = *(const f32x4*)(gamma + t * 8);
    f32x4 g1 = *(const f32x4*)(gamma + t * 8 + 4);
    f32x4 b0 = *(const f32x4*)(beta + t * 8);
    f32x4 b1 = *(const f32x4*)(beta + t * 8 + 4);
    bf16x8 o;
#pragma unroll
    for (int i = 0; i < 4; i++) {
        o[i]     = (bf16_t)((f[i]     - mu) * rs * g0[i] + b0[i]);
        o[i + 4] = (bf16_t)((f[i + 4] - mu) * rs * g1[i] + b1[i]);
    }
    *(bf16x8*)(xn + (size_t)row * DIM + t * 8) = o;
}

// ---------- GEMM: C[MxN] = A[MxK] * Bt[NxK]^T, bf16 in, fp32 accum, OT out ---
// 128x128 tile, BK=32, split-K via blockIdx.z: slice z covers K range
// [z*Kper, (z+1)*Kper) and writes to C + z*M*N. TAG distinguishes dispatches.
template <int TAG, typename OT>
__global__ __launch_bounds__(256) void gemm_bt(const bf16_t* __restrict__ A,
                                               const bf16_t* __restrict__ Bt,
                                               OT* __restrict__ C,
                                               int M, int N, int K, int Kper,
                                               float scale) {
    __shared__ __align__(16) bf16_t lA[128 * 32];
    __shared__ __align__(16) bf16_t lB[128 * 32];
    int tid = threadIdx.x;
    int w = tid >> 6, lane = tid & 63;
    int wm = w >> 1, wn = w & 1;
    int bm0 = blockIdx.y * 128, bn0 = blockIdx.x * 128;
    int z = blockIdx.z;
    int kbase = z * Kper;
    int q = lane >> 4, l16 = lane & 15;

    int c0 = w * 64 + lane;
    int r0 = c0 >> 2, cc0 = c0 & 3;
    int c1 = 256 + c0;
    int r1 = c1 >> 2, cc1 = c1 & 3;
    const bf16_t* pA0 = A + (size_t)(bm0 + r0) * K + kbase + cc0 * 8;
    const bf16_t* pA1 = A + (size_t)(bm0 + r1) * K + kbase + cc1 * 8;
    const bf16_t* pB0 = Bt + (size_t)(bn0 + r0) * K + kbase + cc0 * 8;
    const bf16_t* pB1 = Bt + (size_t)(bn0 + r1) * K + kbase + cc1 * 8;
    bf16_t* lA0 = lA + w * 512;
    bf16_t* lA1 = lA + 2048 + w * 512;
    bf16_t* lB0 = lB + w * 512;
    bf16_t* lB1 = lB + 2048 + w * 512;

    f32x4 acc[4][4];
#pragma unroll
    for (int i = 0; i < 4; i++)
#pragma unroll
        for (int j = 0; j < 4; j++)
            acc[i][j] = (f32x4){0.f, 0.f, 0.f, 0.f};

    for (int k0 = 0; k0 < Kper; k0 += 32) {
        __syncthreads();
        gld_lds16(pA0 + k0, lA0);
        gld_lds16(pA1 + k0, lA1);
        gld_lds16(pB0 + k0, lB0);
        gld_lds16(pB1 + k0, lB1);
        __syncthreads();

        bf16x8 af[4], bfr[4];
#pragma unroll
        for (int mt = 0; mt < 4; mt++)
            af[mt] = *(const bf16x8*)(lA + (wm * 64 + mt * 16 + l16) * 32 + q * 8);
#pragma unroll
        for (int nt = 0; nt < 4; nt++)
            bfr[nt] = *(const bf16x8*)(lB + (wn * 64 + nt * 16 + l16) * 32 + q * 8);
#pragma unroll
        for (int mt = 0; mt < 4; mt++)
#pragma unroll
            for (int nt = 0; nt < 4; nt++)
                acc[mt][nt] = __builtin_amdgcn_mfma_f32_16x16x32_bf16(af[mt], bfr[nt], acc[mt][nt], 0, 0, 0);
    }

    OT* Cz = C + (size_t)z * M * N;
#pragma unroll
    for (int mt = 0; mt < 4; mt++)
#pragma unroll
        for (int nt = 0; nt < 4; nt++)
#pragma unroll
            for (int r = 0; r < 4; r++) {
                int row = bm0 + wm * 64 + mt * 16 + q * 4 + r;
                int col = bn0 + wn * 64 + nt * 16 + l16;
                Cz[(size_t)row * N + col] = (OT)(acc[mt][nt][r] * scale);
            }
}

// ---------- reduce 4 bf16 split-K slices -> bf16, with scale ------------------
__global__ __launch_bounds__(256) void reduce4_k(const bf16_t* __restrict__ p,
                                                 bf16_t* __restrict__ o,
                                                 size_t n, float scale) {
    size_t i = ((size_t)blockIdx.x * 256 + threadIdx.x) * 8;
    bf16x8 a0 = *(const bf16x8*)(p + i);
    bf16x8 a1 = *(const bf16x8*)(p + n + i);
    bf16x8 a2 = *(const bf16x8*)(p + 2 * n + i);
    bf16x8 a3 = *(const bf16x8*)(p + 3 * n + i);
    bf16x8 r;
#pragma unroll
    for (int u = 0; u < 8; u++)
        r[u] = (bf16_t)(((float)a0[u] + (float)a1[u] + (float)a2[u] + (float)a3[u]) * scale);
    *(bf16x8*)(o + i) = r;
}

// ---------- cumsum + bucket build ---------------------------------------------
__global__ __launch_bounds__(256) void cumsum_bucket_k(const void* __restrict__ locs,
                                                       int* __restrict__ bcount,
                                                       int* __restrict__ bidx) {
    int b = blockIdx.x, t = threadIdx.x;
    const unsigned* up = (const unsigned*)locs;
    const int* ip = (const int*)locs;
    const unsigned char* bp = (const unsigned char*)locs;
    const float* fp = (const float*)locs;

    if (t < T_IMG) bcount[b * T_IMG + t] = 0;

    int other = 0, nf = 0;
#pragma unroll
    for (int i = 0; i < 8; i++) {
        unsigned wv = up[t * 8 + i];
        nf    += (wv == 0x3F800000u);
        other += (wv != 0u && wv != 1u && wv != 0x3F800000u);
    }
#pragma unroll
    for (int off = 32; off > 0; off >>= 1) { other += __shfl_xor(other, off); nf += __shfl_xor(nf, off); }
    __shared__ int so[4], sf[4];
    int wid = t >> 6, lane = t & 63;
    if (lane == 0) { so[wid] = other; sf[wid] = nf; }
    __syncthreads();
    other = so[0] + so[1] + so[2] + so[3];
    nf    = sf[0] + sf[1] + sf[2] + sf[3];
    int mode = (other > 0) ? 0 : ((nf > 0) ? 2 : 1);   // 0=u8, 1=i32, 2=f32

    int v[8];
    int s = 0;
#pragma unroll
    for (int i = 0; i < 8; i++) {
        int idx = b * T_TXT + t * 8 + i;
        int xv;
        if (mode == 1)      xv = ip[idx];
        else if (mode == 0) xv = (int)bp[idx];
        else                xv = (fp[idx] != 0.f) ? 1 : 0;
        v[i] = xv;
        s += xv;
    }
    __shared__ int sc[256];
    sc[t] = s;
    __syncthreads();
    for (int off = 1; off < 256; off <<= 1) {
        int add = (t >= off) ? sc[t - off] : 0;
        __syncthreads();
        sc[t] += add;
        __syncthreads();
    }
    int run = sc[t] - s;
#pragma unroll
    for (int i = 0; i < 8; i++) {
        run += v[i];
        if (run > 0) {
            int bk = b * T_IMG + run - 1;
            int pos = atomicAdd(&bcount[bk], 1);
            bidx[bk * T_TXT + pos] = b * T_TXT + t * 8 + i;
        }
    }
}

// ---------- MFMA bucketed attention -------------------------------------------
__global__ __launch_bounds__(256) void attn_mfma_k(const bf16_t* __restrict__ q,
                                                   const bf16_t* __restrict__ kv,
                                                   const int* __restrict__ bcount,
                                                   const int* __restrict__ bidx,
                                                   bf16_t* __restrict__ aout) {
    __shared__ __align__(16) bf16_t lK[64 * 64];
    __shared__ __align__(16) bf16_t lVt[64 * 64];
    __shared__ __align__(16) bf16_t lP[4][16 * 64];

    int bucket = blockIdx.x >> 3;
    int h = blockIdx.x & 7;
    int n_q = bcount[bucket];
    if (n_q <= 0) return;
    int b = bucket >> 3;
    int timg = bucket & 7;
    size_t krow0 = (size_t)(b * (T_IMG * N_LAT) + timg * N_LAT);

    int tid = threadIdx.x;
    int wid = tid >> 6, lane = tid & 63;
    int quad = lane >> 4, l16 = lane & 15;

    {
        const bf16_t* s0 = kv + (krow0 + 16 * wid + (lane >> 3)) * (2 * INNER) + h * DHEAD + (lane & 7) * 8;
        const bf16_t* s1 = kv + (krow0 + 16 * wid + 8 + (lane >> 3)) * (2 * INNER) + h * DHEAD + (lane & 7) * 8;
        gld_lds16(s0, lK + wid * 1024);
        gld_lds16(s1, lK + wid * 1024 + 512);
    }
    {
        int key = tid & 63, dblk = tid >> 6;
        const bf16_t* vsrc = kv + (krow0 + key) * (2 * INNER) + INNER + h * DHEAD + dblk * 16;
        bf16x8 v0 = *(const bf16x8*)vsrc;
        bf16x8 v1 = *(const bf16x8*)(vsrc + 8);
#pragma unroll
        for (int u = 0; u < 8; u++) {
            lVt[(dblk * 16 + u) * 64 + key]     = v0[u];
            lVt[(dblk * 16 + 8 + u) * 64 + key] = v1[u];
        }
    }
    __syncthreads();

    const int* bl = bidx + (size_t)bucket * T_TXT;
    for (int c0 = wid * 16; c0 < n_q; c0 += 64) {
        int qi = bl[c0 + ((c0 + l16 < n_q) ? l16 : 0)];

        const bf16_t* qrow = q + (size_t)qi * INNER + h * DHEAD + quad * 8;
        bf16x8 qf0 = *(const bf16x8*)qrow;
        bf16x8 qf1 = *(const bf16x8*)(qrow + 32);
        f32x4 s[4];
#pragma unroll
        for (int nt = 0; nt < 4; nt++) s[nt] = (f32x4){0.f, 0.f, 0.f, 0.f};
#pragma unroll
        for (int nt = 0; nt < 4; nt++) {
            bf16x8 kf0 = *(const bf16x8*)(lK + (l16 + 16 * nt) * 64 + quad * 8);
            bf16x8 kf1 = *(const bf16x8*)(lK + (l16 + 16 * nt) * 64 + 32 + quad * 8);
            s[nt] = __builtin_amdgcn_mfma_f32_16x16x32_bf16(qf0, kf0, s[nt], 0, 0, 0);
            s[nt] = __builtin_amdgcn_mfma_f32_16x16x32_bf16(qf1, kf1, s[nt], 0, 0, 0);
        }

        float mr[4];
#pragma unroll
        for (int r = 0; r < 4; r++) {
            float m = fmaxf(fmaxf(s[0][r], s[1][r]), fmaxf(s[2][r], s[3][r]));
#pragma unroll
            for (int off = 8; off >= 1; off >>= 1) m = fmaxf(m, __shfl_xor(m, off));
            mr[r] = m;
        }
        float p[4][4];
#pragma unroll
        for (int nt = 0; nt < 4; nt++)
#pragma unroll
            for (int r = 0; r < 4; r++)
                p[nt][r] = __expf(s[nt][r] - mr[r]);
#pragma unroll
        for (int r = 0; r < 4; r++) {
            float tsum = p[0][r] + p[1][r] + p[2][r] + p[3][r];
#pragma unroll
            for (int off = 8; off >= 1; off >>= 1) tsum += __shfl_xor(tsum, off);
            float inv = 1.0f / tsum;
            p[0][r] *= inv; p[1][r] *= inv; p[2][r] *= inv; p[3][r] *= inv;
        }

        bf16_t* pt = lP[wid];
#pragma unroll
        for (int nt = 0; nt < 4; nt++)
#pragma unroll
            for (int r = 0; r < 4; r++)
                pt[(quad * 4 + r) * 64 + 16 * nt + l16] = (bf16_t)p[nt][r];
        asm volatile("s_waitcnt lgkmcnt(0)" ::: "memory");

        bf16x8 pf0 = *(const bf16x8*)(pt + l16 * 64 + quad * 8);
        bf16x8 pf1 = *(const bf16x8*)(pt + l16 * 64 + 32 + quad * 8);
        f32x4 o[4];
#pragma unroll
        for (int ntd = 0; ntd < 4; ntd++) o[ntd] = (f32x4){0.f, 0.f, 0.f, 0.f};
#pragma unroll
        for (int ntd = 0; ntd < 4; ntd++) {
            bf16x8 vf0 = *(const bf16x8*)(lVt + (l16 + 16 * ntd) * 64 + quad * 8);
            bf16x8 vf1 = *(const bf16x8*)(lVt + (l16 + 16 * ntd) * 64 + 32 + quad * 8);
            o[ntd] = __builtin_amdgcn_mfma_f32_16x16x32_bf16(pf0, vf0, o[ntd], 0, 0, 0);
            o[ntd] = __builtin_amdgcn_mfma_f32_16x16x32_bf16(pf1, vf1, o[ntd], 0, 0, 0);
        }

#pragma unroll
        for (int r = 0; r < 4; r++) {
            int row = quad * 4 + r;
            int qo = __shfl(qi, row);
            if (c0 + row < n_q) {
                bf16_t* op = aout + (size_t)qo * INNER + h * DHEAD + l16;
#pragma unroll
                for (int ntd = 0; ntd < 4; ntd++)
                    op[16 * ntd] = (bf16_t)o[ntd][r];
            }
        }
    }
}

// ---------- launch ------------------------------------------------------------
extern "C" void kernel_launch(void* const* d_in, const int* in_sizes, int n_in,
                              void* d_out, int out_size, void* d_ws, size_t ws_size,
                              hipStream_t stream) {
    const float* x     = (const float*)d_in[0];
    const float* media = (const float*)d_in[1];
    const void*  locs  = d_in[2];
    const float* gamma = (const float*)d_in[3];
    const float* beta  = (const float*)d_in[4];
    const float* Wq    = (const float*)d_in[5];
    const float* Wkv   = (const float*)d_in[6];
    const float* Wout  = (const float*)d_in[7];
    float* out = (float*)d_out;

    // d_out (64MB fp32) doubles as scratch before GEMM3 overwrites it:
    //   lower 32MB: xn (bf16 LN output, GEMM1's A)
    //   upper 32MB: split-K bf16 partials (GEMM1: 16MB, then GEMM2: 16MB)
    bf16_t* xn   = (bf16_t*)d_out;
    bf16_t* part = (bf16_t*)d_out + (size_t)16 * 1024 * 1024;

    char* p = (char*)d_ws;
    bf16_t* qbuf   = (bf16_t*)p; p += (size_t)8192 * 512 * 2;    // 8 MB
    bf16_t* aout   = (bf16_t*)p; p += (size_t)8192 * 512 * 2;    // 8 MB
    bf16_t* kvbuf  = (bf16_t*)p; p += (size_t)2048 * 1024 * 2;   // 4 MB
    bf16_t* mediab = (bf16_t*)p; p += (size_t)2048 * 1024 * 2;   // 4 MB
    bf16_t* WqT    = (bf16_t*)p; p += (size_t)512 * 2048 * 2;    // 2 MB
    bf16_t* WkvT   = (bf16_t*)p; p += (size_t)1024 * 1024 * 2;   // 2 MB
    bf16_t* WoutT  = (bf16_t*)p; p += (size_t)2048 * 512 * 2;    // 2 MB
    int*    bcount = (int*)p;    p += 32 * sizeof(int);
    int*    bidx   = (int*)p;    p += (size_t)32 * T_TXT * sizeof(int);  // 256 KB

    transpose_cvt_k<<<dim3(512 / 32, 2048 / 32), dim3(32, 8), 0, stream>>>(Wq, WqT, 2048, 512);
    transpose_cvt_k<<<dim3(1024 / 32, 1024 / 32), dim3(32, 8), 0, stream>>>(Wkv, WkvT, 1024, 1024);
    transpose_cvt_k<<<dim3(2048 / 32, 512 / 32), dim3(32, 8), 0, stream>>>(Wout, WoutT, 512, 2048);
    cvt_k<<<(2048 * 1024) / (256 * 8), 256, 0, stream>>>(media, mediab);

    ln_k<<<8192, 256, 0, stream>>>(x, gamma, beta, xn);

    // GEMM1: q_partials = xn @ Wq, split-K=4 (Kper=512), 1024 blocks
    gemm_bt<1, bf16_t><<<dim3(4, 64, 4), 256, 0, stream>>>(xn, WqT, part, 8192, 512, 2048, 512, 1.0f);
    reduce4_k<<<2048, 256, 0, stream>>>(part, qbuf, (size_t)8192 * 512, 0.125f);

    // GEMM2: kv_partials = media @ Wkv, split-K=4 (Kper=256), 512 blocks
    gemm_bt<2, bf16_t><<<dim3(8, 16, 4), 256, 0, stream>>>(mediab, WkvT, part, 2048, 1024, 1024, 256, 1.0f);
    reduce4_k<<<1024, 256, 0, stream>>>(part, kvbuf, (size_t)2048 * 1024, 1.0f);

    cumsum_bucket_k<<<NB, 256, 0, stream>>>(locs, bcount, bidx);

    hipMemsetAsync(aout, 0, (size_t)8192 * 512 * 2, stream);

    attn_mfma_k<<<32 * HEADS, 256, 0, stream>>>(qbuf, kvbuf, bcount, bidx, aout);

    // GEMM3: out = aout @ Wout (fp32 out, no split: 1024 blocks already)
    gemm_bt<3, float><<<dim3(16, 64, 1), 256, 0, stream>>>(aout, WoutT, out, 8192, 2048, 512, 512, 1.0f);
}

// Round 6
// 271.017 us; speedup vs baseline: 1.2909x; 1.1591x over previous
//
#include <hip/hip_runtime.h>
#include <hip/hip_bf16.h>
#include <stdint.h>

typedef __bf16 bf16_t;
typedef __bf16 bf16x8 __attribute__((ext_vector_type(8)));
typedef float f32x4 __attribute__((ext_vector_type(4)));

#define NB      4
#define T_TXT   2048
#define T_IMG   8
#define N_LAT   64
#define DIM     2048
#define DIM_VIS 1024
#define HEADS   8
#define DHEAD   64
#define INNER   512

__device__ __forceinline__ void gld_lds16(const void* g, void* l) {
    __builtin_amdgcn_global_load_lds((const __attribute__((address_space(1))) void*)g,
                                     (__attribute__((address_space(3))) void*)l,
                                     16, 0, 0);
}

// ---------- transpose + fp32->bf16 convert: in fp32 (R x C) -> out bf16 (C x R)
__global__ __launch_bounds__(256) void transpose_cvt_k(const float* __restrict__ in,
                                                       bf16_t* __restrict__ out,
                                                       int R, int C) {
    __shared__ float tile[32][33];
    int c0 = blockIdx.x * 32, r0 = blockIdx.y * 32;
    int x = threadIdx.x, y = threadIdx.y;  // 32 x 8
#pragma unroll
    for (int d = 0; d < 4; d++)
        tile[y + d * 8][x] = in[(size_t)(r0 + y + d * 8) * C + c0 + x];
    __syncthreads();
#pragma unroll
    for (int d = 0; d < 4; d++)
        out[(size_t)(c0 + y + d * 8) * R + r0 + x] = (bf16_t)tile[x][y + d * 8];
}

// ---------- elementwise fp32 -> bf16 ------------------------------------------
__global__ __launch_bounds__(256) void cvt_k(const float* __restrict__ in,
                                             bf16_t* __restrict__ out) {
    int idx = (blockIdx.x * 256 + threadIdx.x) * 8;
    f32x4 a = *(const f32x4*)(in + idx);
    f32x4 b = *(const f32x4*)(in + idx + 4);
    bf16x8 o;
#pragma unroll
    for (int i = 0; i < 4; i++) { o[i] = (bf16_t)a[i]; o[i + 4] = (bf16_t)b[i]; }
    *(bf16x8*)(out + idx) = o;
}

// ---------- LayerNorm: fp32 in, bf16 out; one block per row of 2048 -----------
__global__ __launch_bounds__(256) void ln_k(const float* __restrict__ x,
                                            const float* __restrict__ gamma,
                                            const float* __restrict__ beta,
                                            bf16_t* __restrict__ xn) {
    int row = blockIdx.x;
    int t = threadIdx.x;
    const float* xp = x + (size_t)row * DIM + t * 8;
    f32x4 v0 = *(const f32x4*)xp;
    f32x4 v1 = *(const f32x4*)(xp + 4);
    float f[8];
    float s = 0.f, ss = 0.f;
#pragma unroll
    for (int i = 0; i < 4; i++) { f[i] = v0[i]; f[i + 4] = v1[i]; }
#pragma unroll
    for (int i = 0; i < 8; i++) { s += f[i]; ss += f[i] * f[i]; }
#pragma unroll
    for (int off = 32; off > 0; off >>= 1) { s += __shfl_xor(s, off); ss += __shfl_xor(ss, off); }
    __shared__ float sbuf[4], sbuf2[4];
    int wid = t >> 6, lane = t & 63;
    if (lane == 0) { sbuf[wid] = s; sbuf2[wid] = ss; }
    __syncthreads();
    s  = sbuf[0] + sbuf[1] + sbuf[2] + sbuf[3];
    ss = sbuf2[0] + sbuf2[1] + sbuf2[2] + sbuf2[3];
    float mu  = s * (1.0f / DIM);
    float var = ss * (1.0f / DIM) - mu * mu;
    float rs  = rsqrtf(var + 1e-5f);
    f32x4 g0 = *(const f32x4*)(gamma + t * 8);
    f32x4 g1 = *(const f32x4*)(gamma + t * 8 + 4);
    f32x4 b0 = *(const f32x4*)(beta + t * 8);
    f32x4 b1 = *(const f32x4*)(beta + t * 8 + 4);
    bf16x8 o;
#pragma unroll
    for (int i = 0; i < 4; i++) {
        o[i]     = (bf16_t)((f[i]     - mu) * rs * g0[i] + b0[i]);
        o[i + 4] = (bf16_t)((f[i + 4] - mu) * rs * g1[i] + b1[i]);
    }
    *(bf16x8*)(xn + (size_t)row * DIM + t * 8) = o;
}

// ---------- GEMM: C[MxN] = A[MxK] * Bt[NxK]^T, bf16 in, fp32 accum, OT out ---
// 128x128 tile, BK=32, split-K via blockIdx.z: slice z covers K range
// [z*Kper, (z+1)*Kper) and writes to C + z*M*N. TAG distinguishes dispatches.
template <int TAG, typename OT>
__global__ __launch_bounds__(256) void gemm_bt(const bf16_t* __restrict__ A,
                                               const bf16_t* __restrict__ Bt,
                                               OT* __restrict__ C,
                                               int M, int N, int K, int Kper,
                                               float scale) {
    __shared__ __align__(16) bf16_t lA[128 * 32];
    __shared__ __align__(16) bf16_t lB[128 * 32];
    int tid = threadIdx.x;
    int w = tid >> 6, lane = tid & 63;
    int wm = w >> 1, wn = w & 1;
    int bm0 = blockIdx.y * 128, bn0 = blockIdx.x * 128;
    int z = blockIdx.z;
    int kbase = z * Kper;
    int q = lane >> 4, l16 = lane & 15;

    int c0 = w * 64 + lane;
    int r0 = c0 >> 2, cc0 = c0 & 3;
    int c1 = 256 + c0;
    int r1 = c1 >> 2, cc1 = c1 & 3;
    const bf16_t* pA0 = A + (size_t)(bm0 + r0) * K + kbase + cc0 * 8;
    const bf16_t* pA1 = A + (size_t)(bm0 + r1) * K + kbase + cc1 * 8;
    const bf16_t* pB0 = Bt + (size_t)(bn0 + r0) * K + kbase + cc0 * 8;
    const bf16_t* pB1 = Bt + (size_t)(bn0 + r1) * K + kbase + cc1 * 8;
    bf16_t* lA0 = lA + w * 512;
    bf16_t* lA1 = lA + 2048 + w * 512;
    bf16_t* lB0 = lB + w * 512;
    bf16_t* lB1 = lB + 2048 + w * 512;

    f32x4 acc[4][4];
#pragma unroll
    for (int i = 0; i < 4; i++)
#pragma unroll
        for (int j = 0; j < 4; j++)
            acc[i][j] = (f32x4){0.f, 0.f, 0.f, 0.f};

    for (int k0 = 0; k0 < Kper; k0 += 32) {
        __syncthreads();
        gld_lds16(pA0 + k0, lA0);
        gld_lds16(pA1 + k0, lA1);
        gld_lds16(pB0 + k0, lB0);
        gld_lds16(pB1 + k0, lB1);
        __syncthreads();

        bf16x8 af[4], bfr[4];
#pragma unroll
        for (int mt = 0; mt < 4; mt++)
            af[mt] = *(const bf16x8*)(lA + (wm * 64 + mt * 16 + l16) * 32 + q * 8);
#pragma unroll
        for (int nt = 0; nt < 4; nt++)
            bfr[nt] = *(const bf16x8*)(lB + (wn * 64 + nt * 16 + l16) * 32 + q * 8);
#pragma unroll
        for (int mt = 0; mt < 4; mt++)
#pragma unroll
            for (int nt = 0; nt < 4; nt++)
                acc[mt][nt] = __builtin_amdgcn_mfma_f32_16x16x32_bf16(af[mt], bfr[nt], acc[mt][nt], 0, 0, 0);
    }

    OT* Cz = C + (size_t)z * M * N;
#pragma unroll
    for (int mt = 0; mt < 4; mt++)
#pragma unroll
        for (int nt = 0; nt < 4; nt++)
#pragma unroll
            for (int r = 0; r < 4; r++) {
                int row = bm0 + wm * 64 + mt * 16 + q * 4 + r;
                int col = bn0 + wn * 64 + nt * 16 + l16;
                Cz[(size_t)row * N + col] = (OT)(acc[mt][nt][r] * scale);
            }
}

// ---------- reduce 4 bf16 split-K slices -> bf16, with scale ------------------
__global__ __launch_bounds__(256) void reduce4_k(const bf16_t* __restrict__ p,
                                                 bf16_t* __restrict__ o,
                                                 size_t n, float scale) {
    size_t i = ((size_t)blockIdx.x * 256 + threadIdx.x) * 8;
    bf16x8 a0 = *(const bf16x8*)(p + i);
    bf16x8 a1 = *(const bf16x8*)(p + n + i);
    bf16x8 a2 = *(const bf16x8*)(p + 2 * n + i);
    bf16x8 a3 = *(const bf16x8*)(p + 3 * n + i);
    bf16x8 r;
#pragma unroll
    for (int u = 0; u < 8; u++)
        r[u] = (bf16_t)(((float)a0[u] + (float)a1[u] + (float)a2[u] + (float)a3[u]) * scale);
    *(bf16x8*)(o + i) = r;
}

// ---------- cumsum + contiguous bucket ranges (NO atomics) --------------------
// Queries attending image t form the contiguous token range
// [pos of t-th media token, pos of (t+1)-th). The media token whose inclusive
// cumsum equals c is the unique writer of bstart[b*8+c-1]; counts come from
// differencing with a T_TXT sentinel (duplicate positions -> empty tail buckets).
// Storage mode auto-detected: uint8 / int32 / fp32 (reads first 8KB only).
__global__ __launch_bounds__(256) void cumsum_bucket_k(const void* __restrict__ locs,
                                                       int* __restrict__ bstart,
                                                       int* __restrict__ bcnt) {
    int b = blockIdx.x, t = threadIdx.x;
    const unsigned* up = (const unsigned*)locs;
    const int* ip = (const int*)locs;
    const unsigned char* bp = (const unsigned char*)locs;
    const float* fp = (const float*)locs;

    int other = 0, nf = 0;
#pragma unroll
    for (int i = 0; i < 8; i++) {
        unsigned wv = up[t * 8 + i];
        nf    += (wv == 0x3F800000u);
        other += (wv != 0u && wv != 1u && wv != 0x3F800000u);
    }
#pragma unroll
    for (int off = 32; off > 0; off >>= 1) { other += __shfl_xor(other, off); nf += __shfl_xor(nf, off); }
    __shared__ int so[4], sf[4];
    int wid = t >> 6, lane = t & 63;
    if (lane == 0) { so[wid] = other; sf[wid] = nf; }
    __syncthreads();
    other = so[0] + so[1] + so[2] + so[3];
    nf    = sf[0] + sf[1] + sf[2] + sf[3];
    int mode = (other > 0) ? 0 : ((nf > 0) ? 2 : 1);   // 0=u8, 1=i32, 2=f32

    int v[8];
    int s = 0;
#pragma unroll
    for (int i = 0; i < 8; i++) {
        int idx = b * T_TXT + t * 8 + i;
        int xv;
        if (mode == 1)      xv = ip[idx];
        else if (mode == 0) xv = (int)bp[idx];
        else                xv = (fp[idx] != 0.f) ? 1 : 0;
        v[i] = xv;
        s += xv;
    }
    __shared__ int sc[256];
    __shared__ int sstart[T_IMG];
    if (t < T_IMG) sstart[t] = T_TXT;   // sentinel
    sc[t] = s;
    __syncthreads();
    for (int off = 1; off < 256; off <<= 1) {
        int add = (t >= off) ? sc[t - off] : 0;
        __syncthreads();
        sc[t] += add;
        __syncthreads();
    }
    int run = sc[t] - s;   // exclusive prefix of this thread's chunk
#pragma unroll
    for (int i = 0; i < 8; i++) {
        run += v[i];
        if (v[i] && run <= T_IMG) sstart[run - 1] = t * 8 + i;  // unique writer
    }
    __syncthreads();
    if (t < T_IMG) {
        int st = sstart[t];
        int nx = (t + 1 < T_IMG) ? sstart[t + 1] : T_TXT;
        bstart[b * T_IMG + t] = st;
        bcnt[b * T_IMG + t]   = nx - st;   // 0 for empty tail buckets
    }
}

// ---------- MFMA bucketed attention (contiguous query ranges) -----------------
// Block = (bucket = b*8 + timg, head). Stages K_h [64x64] row-major and
// V_h transposed [d][key] into LDS; each wave handles 16-query chunks:
// QK^T (8 MFMA) -> quad-shuffle softmax -> P via wave-private LDS (C->A layout)
// -> PV (8 MFMA) -> store. q is pre-scaled by 0.125.
__global__ __launch_bounds__(256) void attn_mfma_k(const bf16_t* __restrict__ q,
                                                   const bf16_t* __restrict__ kv,
                                                   const int* __restrict__ bstart,
                                                   const int* __restrict__ bcnt,
                                                   bf16_t* __restrict__ aout) {
    __shared__ __align__(16) bf16_t lK[64 * 64];
    __shared__ __align__(16) bf16_t lVt[64 * 64];
    __shared__ __align__(16) bf16_t lP[4][16 * 64];

    int bucket = blockIdx.x >> 3;
    int h = blockIdx.x & 7;
    int n_q = bcnt[bucket];
    if (n_q <= 0) return;
    int b = bucket >> 3;
    int timg = bucket & 7;
    int row0 = b * T_TXT + bstart[bucket];   // first query row (global)
    size_t krow0 = (size_t)(b * (T_IMG * N_LAT) + timg * N_LAT);

    int tid = threadIdx.x;
    int wid = tid >> 6, lane = tid & 63;
    int quad = lane >> 4, l16 = lane & 15;

    {
        const bf16_t* s0 = kv + (krow0 + 16 * wid + (lane >> 3)) * (2 * INNER) + h * DHEAD + (lane & 7) * 8;
        const bf16_t* s1 = kv + (krow0 + 16 * wid + 8 + (lane >> 3)) * (2 * INNER) + h * DHEAD + (lane & 7) * 8;
        gld_lds16(s0, lK + wid * 1024);
        gld_lds16(s1, lK + wid * 1024 + 512);
    }
    {
        int key = tid & 63, dblk = tid >> 6;
        const bf16_t* vsrc = kv + (krow0 + key) * (2 * INNER) + INNER + h * DHEAD + dblk * 16;
        bf16x8 v0 = *(const bf16x8*)vsrc;
        bf16x8 v1 = *(const bf16x8*)(vsrc + 8);
#pragma unroll
        for (int u = 0; u < 8; u++) {
            lVt[(dblk * 16 + u) * 64 + key]     = v0[u];
            lVt[(dblk * 16 + 8 + u) * 64 + key] = v1[u];
        }
    }
    __syncthreads();

    for (int c0 = wid * 16; c0 < n_q; c0 += 64) {
        int qi = row0 + c0 + ((c0 + l16 < n_q) ? l16 : 0);   // contiguous rows

        const bf16_t* qrow = q + (size_t)qi * INNER + h * DHEAD + quad * 8;
        bf16x8 qf0 = *(const bf16x8*)qrow;
        bf16x8 qf1 = *(const bf16x8*)(qrow + 32);
        f32x4 s[4];
#pragma unroll
        for (int nt = 0; nt < 4; nt++) s[nt] = (f32x4){0.f, 0.f, 0.f, 0.f};
#pragma unroll
        for (int nt = 0; nt < 4; nt++) {
            bf16x8 kf0 = *(const bf16x8*)(lK + (l16 + 16 * nt) * 64 + quad * 8);
            bf16x8 kf1 = *(const bf16x8*)(lK + (l16 + 16 * nt) * 64 + 32 + quad * 8);
            s[nt] = __builtin_amdgcn_mfma_f32_16x16x32_bf16(qf0, kf0, s[nt], 0, 0, 0);
            s[nt] = __builtin_amdgcn_mfma_f32_16x16x32_bf16(qf1, kf1, s[nt], 0, 0, 0);
        }

        float mr[4];
#pragma unroll
        for (int r = 0; r < 4; r++) {
            float m = fmaxf(fmaxf(s[0][r], s[1][r]), fmaxf(s[2][r], s[3][r]));
#pragma unroll
            for (int off = 8; off >= 1; off >>= 1) m = fmaxf(m, __shfl_xor(m, off));
            mr[r] = m;
        }
        float p[4][4];
#pragma unroll
        for (int nt = 0; nt < 4; nt++)
#pragma unroll
            for (int r = 0; r < 4; r++)
                p[nt][r] = __expf(s[nt][r] - mr[r]);
#pragma unroll
        for (int r = 0; r < 4; r++) {
            float tsum = p[0][r] + p[1][r] + p[2][r] + p[3][r];
#pragma unroll
            for (int off = 8; off >= 1; off >>= 1) tsum += __shfl_xor(tsum, off);
            float inv = 1.0f / tsum;
            p[0][r] *= inv; p[1][r] *= inv; p[2][r] *= inv; p[3][r] *= inv;
        }

        bf16_t* pt = lP[wid];
#pragma unroll
        for (int nt = 0; nt < 4; nt++)
#pragma unroll
            for (int r = 0; r < 4; r++)
                pt[(quad * 4 + r) * 64 + 16 * nt + l16] = (bf16_t)p[nt][r];
        asm volatile("s_waitcnt lgkmcnt(0)" ::: "memory");

        bf16x8 pf0 = *(const bf16x8*)(pt + l16 * 64 + quad * 8);
        bf16x8 pf1 = *(const bf16x8*)(pt + l16 * 64 + 32 + quad * 8);
        f32x4 o[4];
#pragma unroll
        for (int ntd = 0; ntd < 4; ntd++) o[ntd] = (f32x4){0.f, 0.f, 0.f, 0.f};
#pragma unroll
        for (int ntd = 0; ntd < 4; ntd++) {
            bf16x8 vf0 = *(const bf16x8*)(lVt + (l16 + 16 * ntd) * 64 + quad * 8);
            bf16x8 vf1 = *(const bf16x8*)(lVt + (l16 + 16 * ntd) * 64 + 32 + quad * 8);
            o[ntd] = __builtin_amdgcn_mfma_f32_16x16x32_bf16(pf0, vf0, o[ntd], 0, 0, 0);
            o[ntd] = __builtin_amdgcn_mfma_f32_16x16x32_bf16(pf1, vf1, o[ntd], 0, 0, 0);
        }

        // store: query = c0 + quad*4 + r (contiguous), col = l16 + 16*ntd
#pragma unroll
        for (int r = 0; r < 4; r++) {
            int qidx = c0 + quad * 4 + r;
            if (qidx < n_q) {
                bf16_t* op = aout + (size_t)(row0 + qidx) * INNER + h * DHEAD + l16;
#pragma unroll
                for (int ntd = 0; ntd < 4; ntd++)
                    op[16 * ntd] = (bf16_t)o[ntd][r];
            }
        }
    }
}

// ---------- launch ------------------------------------------------------------
extern "C" void kernel_launch(void* const* d_in, const int* in_sizes, int n_in,
                              void* d_out, int out_size, void* d_ws, size_t ws_size,
                              hipStream_t stream) {
    const float* x     = (const float*)d_in[0];
    const float* media = (const float*)d_in[1];
    const void*  locs  = d_in[2];
    const float* gamma = (const float*)d_in[3];
    const float* beta  = (const float*)d_in[4];
    const float* Wq    = (const float*)d_in[5];
    const float* Wkv   = (const float*)d_in[6];
    const float* Wout  = (const float*)d_in[7];
    float* out = (float*)d_out;

    // d_out (64MB fp32) doubles as scratch before GEMM3 overwrites it:
    //   lower 32MB: xn (bf16 LN output, GEMM1's A)
    //   upper 32MB: split-K bf16 partials (GEMM1: 16MB, then GEMM2: 16MB)
    bf16_t* xn   = (bf16_t*)d_out;
    bf16_t* part = (bf16_t*)d_out + (size_t)16 * 1024 * 1024;

    char* p = (char*)d_ws;
    bf16_t* qbuf   = (bf16_t*)p; p += (size_t)8192 * 512 * 2;    // 8 MB
    bf16_t* aout   = (bf16_t*)p; p += (size_t)8192 * 512 * 2;    // 8 MB
    bf16_t* kvbuf  = (bf16_t*)p; p += (size_t)2048 * 1024 * 2;   // 4 MB
    bf16_t* mediab = (bf16_t*)p; p += (size_t)2048 * 1024 * 2;   // 4 MB
    bf16_t* WqT    = (bf16_t*)p; p += (size_t)512 * 2048 * 2;    // 2 MB
    bf16_t* WkvT   = (bf16_t*)p; p += (size_t)1024 * 1024 * 2;   // 2 MB
    bf16_t* WoutT  = (bf16_t*)p; p += (size_t)2048 * 512 * 2;    // 2 MB
    int*    bstart = (int*)p;    p += 32 * sizeof(int);
    int*    bcnt   = (int*)p;    p += 32 * sizeof(int);

    transpose_cvt_k<<<dim3(512 / 32, 2048 / 32), dim3(32, 8), 0, stream>>>(Wq, WqT, 2048, 512);
    transpose_cvt_k<<<dim3(1024 / 32, 1024 / 32), dim3(32, 8), 0, stream>>>(Wkv, WkvT, 1024, 1024);
    transpose_cvt_k<<<dim3(2048 / 32, 512 / 32), dim3(32, 8), 0, stream>>>(Wout, WoutT, 512, 2048);
    cvt_k<<<(2048 * 1024) / (256 * 8), 256, 0, stream>>>(media, mediab);

    ln_k<<<8192, 256, 0, stream>>>(x, gamma, beta, xn);

    // GEMM1: q_partials = xn @ Wq, split-K=4 (Kper=512), 1024 blocks
    gemm_bt<1, bf16_t><<<dim3(4, 64, 4), 256, 0, stream>>>(xn, WqT, part, 8192, 512, 2048, 512, 1.0f);
    reduce4_k<<<2048, 256, 0, stream>>>(part, qbuf, (size_t)8192 * 512, 0.125f);

    // GEMM2: kv_partials = media @ Wkv, split-K=4 (Kper=256), 512 blocks
    gemm_bt<2, bf16_t><<<dim3(8, 16, 4), 256, 0, stream>>>(mediab, WkvT, part, 2048, 1024, 1024, 256, 1.0f);
    reduce4_k<<<1024, 256, 0, stream>>>(part, kvbuf, (size_t)2048 * 1024, 1.0f);

    cumsum_bucket_k<<<NB, 256, 0, stream>>>(locs, bstart, bcnt);

    hipMemsetAsync(aout, 0, (size_t)8192 * 512 * 2, stream);

    attn_mfma_k<<<32 * HEADS, 256, 0, stream>>>(qbuf, kvbuf, bstart, bcnt, aout);

    // GEMM3: out = aout @ Wout (fp32 out, no split: 1024 blocks already)
    gemm_bt<3, float><<<dim3(16, 64, 1), 256, 0, stream>>>(aout, WoutT, out, 8192, 2048, 512, 512, 1.0f);
}